// Round 1
// baseline (239.172 us; speedup 1.0000x reference)
//
#include <hip/hip_runtime.h>

// ClusterAggregator: B=8, N=32768, D=128, C=64, H=64
// out[b,c,:] = sum_{n: ca[b,n]==c} w_n * f[b,n,:],  w = softmax over segment of
// imp = sigmoid(relu(f@W1+b1)@W2+b2).  Softmax shift-invariance: use fixed
// shift 1 (imp in (0,1)) -> e = exp(imp-1), exact after normalization.

#define B_ 8
#define N_ 32768
#define D_ 128
#define C_ 64
#define H_ 64

#define ROWS_PER_BLOCK 512
#define NBLOCKS ((B_ * N_) / ROWS_PER_BLOCK)   // 512
#define NTHREADS 256
#define NWAVES 4

__device__ __forceinline__ float rl(float x, int lane) {
    return __int_as_float(__builtin_amdgcn_readlane(__float_as_int(x), lane));
}

__global__ __launch_bounds__(NTHREADS, 2)
void ca_fused_kernel(const float* __restrict__ features,
                     const int* __restrict__ ca,
                     const float* __restrict__ W1,
                     const float* __restrict__ b1,
                     const float* __restrict__ W2,
                     const float* __restrict__ b2,
                     float* __restrict__ out_sums,   // [B*C*D], pre-zeroed, atomic acc
                     float* __restrict__ denoms)     // [B*C], pre-zeroed, atomic acc
{
    __shared__ float bins[C_ * D_];   // 32 KB
    __shared__ float dbins[C_];

    const int tid  = threadIdx.x;
    const int lane = tid & 63;
    const int wave = tid >> 6;

    const int chunks_per_batch = N_ / ROWS_PER_BLOCK;     // 64
    const int b     = blockIdx.x / chunks_per_batch;
    const int chunk = blockIdx.x % chunks_per_batch;
    const int row_base = b * N_ + chunk * ROWS_PER_BLOCK;

    // zero LDS bins
    for (int i = tid; i < C_ * D_; i += NTHREADS) bins[i] = 0.f;
    if (tid < C_) dbins[tid] = 0.f;

    // Lane l holds W1 column l in registers: w1r[d] = W1[d][l]
    float w1r[D_];
#pragma unroll
    for (int d = 0; d < D_; ++d) w1r[d] = W1[d * H_ + lane];
    const float b1l = b1[lane];
    const float w2l = W2[lane];
    const float b2v = b2[0];

    __syncthreads();

    const int rows_per_wave = ROWS_PER_BLOCK / NWAVES;    // 128
    for (int i = 0; i < rows_per_wave; ++i) {
        const int row = row_base + i * NWAVES + wave;
        const float* frow = features + (long long)row * D_;
        // lane q holds f[q] (u) and f[64+q] (v); both loads coalesced 256B
        const float u = frow[lane];
        const float v = frow[64 + lane];

        // h[lane] = sum_d f[d] * W1[d][lane]; broadcast f via v_readlane
        float a0 = 0.f, a1 = 0.f, a2 = 0.f, a3 = 0.f;
#pragma unroll
        for (int d = 0; d < 64; d += 2) {
            const float x0 = rl(u, d);
            const float x1 = rl(u, d + 1);
            const float y0 = rl(v, d);
            const float y1 = rl(v, d + 1);
            a0 = fmaf(x0, w1r[d],          a0);
            a1 = fmaf(x1, w1r[d + 1],      a1);
            a2 = fmaf(y0, w1r[64 + d],     a2);
            a3 = fmaf(y1, w1r[64 + d + 1], a3);
        }
        float h = (a0 + a1) + (a2 + a3) + b1l;
        h = fmaxf(h, 0.f);
        float t = h * w2l;
#pragma unroll
        for (int off = 32; off > 0; off >>= 1) t += __shfl_xor(t, off, 64);
        const float pre  = t + b2v;
        const float impv = 1.f / (1.f + __expf(-pre));
        const float e    = __expf(impv - 1.f);

        const int c = ca[row];   // uniform per wave -> scalar load
        // bins[c][lane] / bins[c][64+lane]: bank stride 1 -> 2-way (free)
        atomicAdd(&bins[c * D_ + lane],      e * u);
        atomicAdd(&bins[c * D_ + 64 + lane], e * v);
        if (lane == 0) atomicAdd(&dbins[c], e);
    }

    __syncthreads();
    // flush block partials to global accumulators
    for (int i = tid; i < C_ * D_; i += NTHREADS)
        atomicAdd(&out_sums[b * (C_ * D_) + i], bins[i]);
    if (tid < C_) atomicAdd(&denoms[b * C_ + tid], dbins[tid]);
}

__global__ void ca_zero_kernel(float* __restrict__ out_sums,
                               float* __restrict__ denoms)
{
    const int i = blockIdx.x * blockDim.x + threadIdx.x;
    if (i < B_ * C_ * D_) out_sums[i] = 0.f;
    if (i < B_ * C_)      denoms[i] = 0.f;
}

__global__ void ca_finalize_kernel(float* __restrict__ out_sums,
                                   const float* __restrict__ denoms)
{
    const int i = blockIdx.x * blockDim.x + threadIdx.x;
    if (i >= B_ * C_ * D_) return;
    const int bc = i >> 7;                 // /D_
    const float den = denoms[bc];
    const float v = out_sums[i];
    out_sums[i] = (den > 0.f) ? (v / den) : 0.f;
}

extern "C" void kernel_launch(void* const* d_in, const int* in_sizes, int n_in,
                              void* d_out, int out_size, void* d_ws, size_t ws_size,
                              hipStream_t stream) {
    const float* features = (const float*)d_in[0];
    const int*   ca       = (const int*)  d_in[1];
    const float* W1       = (const float*)d_in[2];
    const float* b1       = (const float*)d_in[3];
    const float* W2       = (const float*)d_in[4];
    const float* b2       = (const float*)d_in[5];
    // d_in[6] = num_clusters (hardcoded 64)

    float* out    = (float*)d_out;          // [B*C*D] = 65536, used as accumulator
    float* denoms = (float*)d_ws;           // [B*C] = 512 floats in workspace

    ca_zero_kernel<<<(B_ * C_ * D_ + 255) / 256, 256, 0, stream>>>(out, denoms);
    ca_fused_kernel<<<NBLOCKS, NTHREADS, 0, stream>>>(features, ca, W1, b1, W2, b2,
                                                      out, denoms);
    ca_finalize_kernel<<<(B_ * C_ * D_ + 255) / 256, 256, 0, stream>>>(out, denoms);
}

// Round 2
// 201.272 us; speedup vs baseline: 1.1883x; 1.1883x over previous
//
#include <hip/hip_runtime.h>

// ClusterAggregator: B=8, N=32768, D=128, C=64, H=64
// out[b,c,:] = sum_{n: ca[b,n]==c} w_n * f[b,n,:], w = segment softmax of
// imp = sigmoid(relu(f@W1+b1)@W2+b2). Softmax shift-invariance: fixed shift 1
// (imp in (0,1)) -> e = exp(imp-1), exact after normalization.
// Matmul on bf16 MFMA 16x16x32; aggregation in fp32 (bf16-rounded features).

#define B_ 8
#define N_ 32768
#define D_ 128
#define C_ 64
#define H_ 64

#define NTHREADS 256
#define NWAVES 4
#define ROWS_PER_BLOCK 512
#define NBLOCKS ((B_ * N_) / ROWS_PER_BLOCK)   // 512
#define TILES 8            // 8 tiles * 16 rows = 128 rows per wave
#define FTS 136            // ushort stride of staged row (128 + 8 pad)

typedef float f32x4 __attribute__((ext_vector_type(4)));
typedef short s16x8 __attribute__((ext_vector_type(8)));

__device__ __forceinline__ short bf16rne(float x) {
    unsigned u = __float_as_uint(x);
    u = (u + 0x7FFFu + ((u >> 16) & 1u)) >> 16;
    return (short)u;
}
__device__ __forceinline__ float bf16tof(unsigned short s) {
    return __uint_as_float(((unsigned)s) << 16);
}

__global__ __launch_bounds__(NTHREADS, 2)
void ca_fused_kernel(const float* __restrict__ features,
                     const int* __restrict__ ca,
                     const float* __restrict__ W1,
                     const float* __restrict__ b1,
                     const float* __restrict__ W2,
                     const float* __restrict__ b2,
                     float* __restrict__ out_sums,   // [B*C*D] atomic acc
                     float* __restrict__ denoms)     // [B*C]  atomic acc
{
    __shared__ float bins[C_ * D_];                      // 32 KB
    __shared__ float dbins[C_];
    __shared__ unsigned short ftile[NWAVES][16 * FTS];   // 17 KB (bf16 rows)

    const int tid  = threadIdx.x;
    const int lane = tid & 63;
    const int wave = tid >> 6;
    const int m    = lane & 15;   // A-row / B-col index within fragment
    const int kb   = lane >> 4;   // k-group

    const int chunks_per_batch = N_ / ROWS_PER_BLOCK;    // 64
    const int b = blockIdx.x / chunks_per_batch;

    for (int i = tid; i < C_ * D_; i += NTHREADS) bins[i] = 0.f;
    if (tid < C_) dbins[tid] = 0.f;

    // B fragments (persistent): bfr[ks][nt][j] = bf16(W1[ks*32+kb*8+j][nt*16+m])
    s16x8 bfr[4][4];
#pragma unroll
    for (int ks = 0; ks < 4; ++ks)
#pragma unroll
        for (int nt = 0; nt < 4; ++nt)
#pragma unroll
            for (int j = 0; j < 8; ++j)
                bfr[ks][nt][j] = bf16rne(W1[(ks * 32 + kb * 8 + j) * H_ + nt * 16 + m]);

    float b1v[4], w2v[4];
#pragma unroll
    for (int nt = 0; nt < 4; ++nt) {
        b1v[nt] = b1[nt * 16 + m];
        w2v[nt] = W2[nt * 16 + m];
    }
    const float b2v = b2[0];

    __syncthreads();

    unsigned short* ftw = &ftile[wave][0];
    const int row_block0 = blockIdx.x * ROWS_PER_BLOCK;

    for (int t = 0; t < TILES; ++t) {
        const int row0 = row_block0 + wave * (16 * TILES) + t * 16;
        const long long grow = row0 + m;
        const float4* fp = (const float4*)features + grow * 32;

        // cluster ids for the 16 rows (lane r < 16 holds row r's id)
        int cv = 0;
        if (lane < 16) cv = ca[row0 + lane];

        // ---- load 16x128 tile, convert to bf16 A-frags, stage bf16 to LDS
        s16x8 af[4];
#pragma unroll
        for (int ks = 0; ks < 4; ++ks) {
            const float4 fa = fp[ks * 8 + kb * 2];
            const float4 fb = fp[ks * 8 + kb * 2 + 1];
            s16x8 a;
            a[0] = bf16rne(fa.x); a[1] = bf16rne(fa.y);
            a[2] = bf16rne(fa.z); a[3] = bf16rne(fa.w);
            a[4] = bf16rne(fb.x); a[5] = bf16rne(fb.y);
            a[6] = bf16rne(fb.z); a[7] = bf16rne(fb.w);
            af[ks] = a;
            *reinterpret_cast<s16x8*>(&ftw[m * FTS + ks * 32 + kb * 8]) = a;
        }

        // ---- MFMA: h[16 rows][64] = f @ W1
        f32x4 acc[4];
#pragma unroll
        for (int nt = 0; nt < 4; ++nt) acc[nt] = (f32x4){0.f, 0.f, 0.f, 0.f};
#pragma unroll
        for (int ks = 0; ks < 4; ++ks)
#pragma unroll
            for (int nt = 0; nt < 4; ++nt)
                acc[nt] = __builtin_amdgcn_mfma_f32_16x16x32_bf16(
                    af[ks], bfr[ks][nt], acc[nt], 0, 0, 0);

        // ---- epilogue: relu, @W2, sigmoid, e = exp(imp-1)
        // acc[nt][r] = h[row=(lane>>4)*4+r][hcol=nt*16+(lane&15)]
        float p[4];
#pragma unroll
        for (int r = 0; r < 4; ++r) {
            float s = 0.f;
#pragma unroll
            for (int nt = 0; nt < 4; ++nt)
                s = fmaf(fmaxf(acc[nt][r] + b1v[nt], 0.f), w2v[nt], s);
#pragma unroll
            for (int off = 1; off < 16; off <<= 1)
                s += __shfl_xor(s, off, 64);
            const float pre = s + b2v;
            const float imp = 1.f / (1.f + __expf(-pre));
            p[r] = __expf(imp - 1.f);
        }
        // lane provides e for row 4*(lane>>4)+(lane&3); fetch e for row m
        const int q = lane & 3;
        const float prov = (q == 0) ? p[0] : (q == 1) ? p[1] : (q == 2) ? p[2] : p[3];
        const int srcl = ((m >> 2) << 4) | (m & 3);
        const float eL = __shfl(prov, srcl, 64);   // e for row (lane&15)
        if (lane < 16) atomicAdd(&dbins[cv], eL);

        // stage writes must land before row-reads
        asm volatile("s_waitcnt lgkmcnt(0)" ::: "memory");

        // ---- aggregate: one row per instruction, d = lane (conflict-free)
#pragma unroll
        for (int r = 0; r < 16; ++r) {
            const float e = __shfl(eL, r, 64);   // const lane -> v_readlane
            const int   c = __shfl(cv, r, 64);
            const float v0 = bf16tof(ftw[r * FTS + lane]);
            const float v1 = bf16tof(ftw[r * FTS + 64 + lane]);
            atomicAdd(&bins[c * D_ + lane],      e * v0);
            atomicAdd(&bins[c * D_ + 64 + lane], e * v1);
        }
    }

    __syncthreads();
    for (int i = tid; i < C_ * D_; i += NTHREADS)
        atomicAdd(&out_sums[b * (C_ * D_) + i], bins[i]);
    if (tid < C_) atomicAdd(&denoms[b * C_ + tid], dbins[tid]);
}

__global__ void ca_zero_kernel(float* __restrict__ out_sums,
                               float* __restrict__ denoms)
{
    const int i = blockIdx.x * blockDim.x + threadIdx.x;
    if (i < B_ * C_ * D_) out_sums[i] = 0.f;
    if (i < B_ * C_)      denoms[i] = 0.f;
}

__global__ void ca_finalize_kernel(float* __restrict__ out_sums,
                                   const float* __restrict__ denoms)
{
    const int i = blockIdx.x * blockDim.x + threadIdx.x;
    if (i >= B_ * C_ * D_) return;
    const int bc = i >> 7;
    const float den = denoms[bc];
    const float v = out_sums[i];
    out_sums[i] = (den > 0.f) ? (v / den) : 0.f;
}

extern "C" void kernel_launch(void* const* d_in, const int* in_sizes, int n_in,
                              void* d_out, int out_size, void* d_ws, size_t ws_size,
                              hipStream_t stream) {
    const float* features = (const float*)d_in[0];
    const int*   ca       = (const int*)  d_in[1];
    const float* W1       = (const float*)d_in[2];
    const float* b1       = (const float*)d_in[3];
    const float* W2       = (const float*)d_in[4];
    const float* b2       = (const float*)d_in[5];

    float* out    = (float*)d_out;   // [B*C*D] accumulator then result
    float* denoms = (float*)d_ws;    // [B*C] in workspace

    ca_zero_kernel<<<(B_ * C_ * D_ + 255) / 256, 256, 0, stream>>>(out, denoms);
    ca_fused_kernel<<<NBLOCKS, NTHREADS, 0, stream>>>(features, ca, W1, b1, W2, b2,
                                                      out, denoms);
    ca_finalize_kernel<<<(B_ * C_ * D_ + 255) / 256, 256, 0, stream>>>(out, denoms);
}